// Round 1
// baseline (336.684 us; speedup 1.0000x reference)
//
#include <hip/hip_runtime.h>
#include <math.h>

#define NB 1024
#define NL 196
#define NA 1024
#define NH 1024

// ---------------------------------------------------------------------------
// Kernel 1: h_att[b,a] = sum_k h_prev[b,k] * W_h[a,k] + b_h[a]
// fp32 (no fp32 MFMA on CDNA4 -> vector ALU), 64x64 tile, BK=32,
// LDS stored k-major (transposed) with stride 72 (16B-aligned rows, 2-way max
// write conflict), register-prefetch double buffering.
// ---------------------------------------------------------------------------
__global__ __launch_bounds__(256) void hatt_gemm_kernel(
    const float* __restrict__ hp,   // [NB, NH]
    const float* __restrict__ Wh,   // [NA, NH]
    const float* __restrict__ bh,   // [NA]
    float* __restrict__ hatt)       // [NB, NA]  (= d_out, overwritten later)
{
    __shared__ float As[32][72];
    __shared__ float Ws[32][72];
    const int t  = threadIdx.x;
    const int lr = t >> 3;          // 0..31 (tile row within half)
    const int lk = (t & 7) << 2;    // 0,4,...,28 (k within tile)
    const int ty = t >> 4;          // 0..15
    const int tx = t & 15;          // 0..15
    const int brow = blockIdx.y << 6;   // b base
    const int bcol = blockIdx.x << 6;   // a base

    const float* Ap = hp + (size_t)(brow + lr) * NH + lk;
    const float* Wp = Wh + (size_t)(bcol + lr) * NH + lk;

    float4 a0 = *(const float4*)(Ap);
    float4 a1 = *(const float4*)(Ap + 32 * NH);
    float4 w0 = *(const float4*)(Wp);
    float4 w1 = *(const float4*)(Wp + 32 * NH);

    float acc[4][4] = {};

    for (int kt = 0; kt < NH / 32; ++kt) {
        // staged regs -> LDS (transposed: [k][row])
        As[lk+0][lr]    = a0.x; As[lk+1][lr]    = a0.y; As[lk+2][lr]    = a0.z; As[lk+3][lr]    = a0.w;
        As[lk+0][lr+32] = a1.x; As[lk+1][lr+32] = a1.y; As[lk+2][lr+32] = a1.z; As[lk+3][lr+32] = a1.w;
        Ws[lk+0][lr]    = w0.x; Ws[lk+1][lr]    = w0.y; Ws[lk+2][lr]    = w0.z; Ws[lk+3][lr]    = w0.w;
        Ws[lk+0][lr+32] = w1.x; Ws[lk+1][lr+32] = w1.y; Ws[lk+2][lr+32] = w1.z; Ws[lk+3][lr+32] = w1.w;
        __syncthreads();

        if (kt + 1 < NH / 32) {  // prefetch next K-tile into registers
            const float* Ap2 = Ap + (kt + 1) * 32;
            const float* Wp2 = Wp + (kt + 1) * 32;
            a0 = *(const float4*)(Ap2);
            a1 = *(const float4*)(Ap2 + 32 * NH);
            w0 = *(const float4*)(Wp2);
            w1 = *(const float4*)(Wp2 + 32 * NH);
        }

        #pragma unroll
        for (int k = 0; k < 32; ++k) {
            float4 av = *(const float4*)&As[k][ty << 2];
            float4 wv = *(const float4*)&Ws[k][tx << 2];
            float ar[4] = {av.x, av.y, av.z, av.w};
            float wr[4] = {wv.x, wv.y, wv.z, wv.w};
            #pragma unroll
            for (int i = 0; i < 4; ++i)
                #pragma unroll
                for (int j = 0; j < 4; ++j)
                    acc[i][j] = fmaf(ar[i], wr[j], acc[i][j]);
        }
        __syncthreads();
    }

    const float4 bias = *(const float4*)&bh[bcol + (tx << 2)];
    #pragma unroll
    for (int i = 0; i < 4; ++i) {
        float4 o;
        o.x = acc[i][0] + bias.x;
        o.y = acc[i][1] + bias.y;
        o.z = acc[i][2] + bias.z;
        o.w = acc[i][3] + bias.w;
        *(float4*)&hatt[(size_t)(brow + (ty << 2) + i) * NA + bcol + (tx << 2)] = o;
    }
}

// ---------------------------------------------------------------------------
// Kernel 2: one block per batch row b.
//  Phase A: wave w computes scores for l = w, w+4, ... (49 each):
//           score = sum_a relu(h_att[b,a] + fproj[b,l,a]) * w_out[a]
//           (h_att & w_out fragments live in registers: lane owns
//            a = lane*4 + c*256, c=0..3)
//  softmax over 196 in LDS
//  Phase B: context[b, t*4..t*4+3] = sum_l alpha_l * features[b,l,t*4..]
//  h_att is read from `out` (written by kernel 1) and the same row is
//  overwritten with context at the end -- block-local, no hazard.
// ---------------------------------------------------------------------------
__global__ __launch_bounds__(256) void attn_main_kernel(
    const float* __restrict__ features,  // [NB, NL, NA]
    const float* __restrict__ fproj,     // [NB, NL, NA]
    const float* __restrict__ wout,      // [NA]
    float* out)                          // [NB, NA]: in = h_att, out = context
{
    __shared__ float s_alpha[NL];
    __shared__ float s_red[4];

    const int t    = threadIdx.x;
    const int lane = t & 63;
    const int wid  = t >> 6;
    const int b    = blockIdx.x;

    // per-lane h_att / w_out fragments (a = lane*4 + c*256)
    const float* hrow = out + (size_t)b * NA;
    float hreg[4][4], wreg[4][4];
    #pragma unroll
    for (int c = 0; c < 4; ++c) {
        float4 h4 = *(const float4*)(hrow + c * 256 + lane * 4);
        float4 w4 = *(const float4*)(wout + c * 256 + lane * 4);
        hreg[c][0] = h4.x; hreg[c][1] = h4.y; hreg[c][2] = h4.z; hreg[c][3] = h4.w;
        wreg[c][0] = w4.x; wreg[c][1] = w4.y; wreg[c][2] = w4.z; wreg[c][3] = w4.w;
    }

    // ---- Phase A: scores ----
    const float* fpb = fproj + (size_t)b * NL * NA;
    #pragma unroll 2
    for (int l = wid; l < NL; l += 4) {
        const float* row = fpb + (size_t)l * NA + lane * 4;
        float4 f[4];
        #pragma unroll
        for (int c = 0; c < 4; ++c) f[c] = *(const float4*)(row + c * 256);
        float p = 0.f;
        #pragma unroll
        for (int c = 0; c < 4; ++c) {
            float fr[4] = {f[c].x, f[c].y, f[c].z, f[c].w};
            #pragma unroll
            for (int j = 0; j < 4; ++j)
                p = fmaf(fmaxf(hreg[c][j] + fr[j], 0.f), wreg[c][j], p);
        }
        #pragma unroll
        for (int m = 32; m; m >>= 1) p += __shfl_xor(p, m, 64);
        if (lane == 0) s_alpha[l] = p;
    }
    __syncthreads();

    // ---- softmax over NL=196 ----
    float sv = (t < NL) ? s_alpha[t] : -INFINITY;
    float mx = sv;
    #pragma unroll
    for (int m = 32; m; m >>= 1) mx = fmaxf(mx, __shfl_xor(mx, m, 64));
    if (lane == 0) s_red[wid] = mx;
    __syncthreads();
    mx = fmaxf(fmaxf(s_red[0], s_red[1]), fmaxf(s_red[2], s_red[3]));
    float e = (t < NL) ? __expf(sv - mx) : 0.f;
    float sm = e;
    #pragma unroll
    for (int m = 32; m; m >>= 1) sm += __shfl_xor(sm, m, 64);
    __syncthreads();                 // all reads of s_red done
    if (lane == 0) s_red[wid] = sm;
    __syncthreads();
    sm = s_red[0] + s_red[1] + s_red[2] + s_red[3];
    if (t < NL) s_alpha[t] = e / sm;
    __syncthreads();

    // ---- Phase B: context ----
    const float* fb = features + (size_t)b * NL * NA + t * 4;
    float4 acc = {0.f, 0.f, 0.f, 0.f};
    #pragma unroll 4
    for (int l = 0; l < NL; ++l) {
        const float al = s_alpha[l];
        float4 f = *(const float4*)(fb + (size_t)l * NA);
        acc.x = fmaf(al, f.x, acc.x);
        acc.y = fmaf(al, f.y, acc.y);
        acc.z = fmaf(al, f.z, acc.z);
        acc.w = fmaf(al, f.w, acc.w);
    }
    *(float4*)(out + (size_t)b * NA + t * 4) = acc;
}

extern "C" void kernel_launch(void* const* d_in, const int* in_sizes, int n_in,
                              void* d_out, int out_size, void* d_ws, size_t ws_size,
                              hipStream_t stream) {
    const float* features = (const float*)d_in[0];  // [1024,196,1024]
    const float* fproj    = (const float*)d_in[1];  // [1024,196,1024]
    const float* hp       = (const float*)d_in[2];  // [1024,1024]
    const float* Wh       = (const float*)d_in[3];  // [1024,1024]
    const float* bh       = (const float*)d_in[4];  // [1024]
    const float* wout     = (const float*)d_in[5];  // [1024]
    // d_in[6] = b_out: softmax(s + c) == softmax(s), provably unused.
    float* out = (float*)d_out;                     // [1024,1024]

    hatt_gemm_kernel<<<dim3(16, 16), 256, 0, stream>>>(hp, Wh, bh, out);
    attn_main_kernel<<<NB, 256, 0, stream>>>(features, fproj, wout, out);
}

// Round 2
// 308.785 us; speedup vs baseline: 1.0904x; 1.0904x over previous
//
#include <hip/hip_runtime.h>
#include <math.h>

#define NB 1024
#define NL 196
#define NA 1024
#define NH 1024

typedef __attribute__((ext_vector_type(8))) short bf16x8;
typedef __attribute__((ext_vector_type(4))) float f32x4;

// f32 -> bf16 round-to-nearest-even, returned as raw bits
__device__ inline short f2bf(float x) {
    unsigned int u = __float_as_uint(x);
    u += 0x7FFFu + ((u >> 16) & 1u);
    return (short)(u >> 16);
}

// ---------------------------------------------------------------------------
// Kernel 1: h_att[b,a] = sum_k h_prev[b,k] * W_h[a,k] + b_h[a]
// bf16 MFMA (16x16x32), 64x64 tile, BK=32. f32 staged from HBM, converted to
// bf16 in registers, stored to LDS [row][k] with pitch 40 bf16 (80 B,
// 16B-aligned rows; fragment b128 reads are 2-way bank aliased = free).
// 4 waves per block, each owns a 32x32 quadrant (2x2 fragments of 16x16).
// ---------------------------------------------------------------------------
__global__ __launch_bounds__(256) void hatt_gemm_mfma(
    const float* __restrict__ hp,   // [NB, NH]
    const float* __restrict__ Wh,   // [NA, NH]
    const float* __restrict__ bh,   // [NA]
    float* __restrict__ hatt)       // [NB, NA]  (= d_out, overwritten later)
{
    __shared__ short As[64][40];
    __shared__ short Ws[64][40];

    const int t   = threadIdx.x;
    const int row = t >> 2;          // 0..63  (staging row)
    const int c8  = (t & 3) << 3;    // 0,8,16,24 (staging k-offset)
    const int brow = blockIdx.y << 6;
    const int bcol = blockIdx.x << 6;

    const float* Ap = hp + (size_t)(brow + row) * NH + c8;
    const float* Wp = Wh + (size_t)(bcol + row) * NH + c8;

    float4 a0 = *(const float4*)(Ap);
    float4 a1 = *(const float4*)(Ap + 4);
    float4 w0 = *(const float4*)(Wp);
    float4 w1 = *(const float4*)(Wp + 4);

    const int lane = t & 63;
    const int wid  = t >> 6;
    const int wr   = (wid >> 1) << 5;   // 0 or 32
    const int wc   = (wid & 1) << 5;    // 0 or 32
    const int l15  = lane & 15;
    const int kof  = (lane >> 4) << 3;  // 0,8,16,24

    f32x4 acc00 = {}, acc01 = {}, acc10 = {}, acc11 = {};

    for (int kt = 0; kt < NH / 32; ++kt) {
        bf16x8 pa, pb;
        pa[0]=f2bf(a0.x); pa[1]=f2bf(a0.y); pa[2]=f2bf(a0.z); pa[3]=f2bf(a0.w);
        pa[4]=f2bf(a1.x); pa[5]=f2bf(a1.y); pa[6]=f2bf(a1.z); pa[7]=f2bf(a1.w);
        pb[0]=f2bf(w0.x); pb[1]=f2bf(w0.y); pb[2]=f2bf(w0.z); pb[3]=f2bf(w0.w);
        pb[4]=f2bf(w1.x); pb[5]=f2bf(w1.y); pb[6]=f2bf(w1.z); pb[7]=f2bf(w1.w);
        *(bf16x8*)&As[row][c8] = pa;
        *(bf16x8*)&Ws[row][c8] = pb;
        __syncthreads();

        if (kt + 1 < NH / 32) {     // register prefetch of next K-tile
            const float* Ap2 = Ap + (kt + 1) * 32;
            const float* Wp2 = Wp + (kt + 1) * 32;
            a0 = *(const float4*)(Ap2);
            a1 = *(const float4*)(Ap2 + 4);
            w0 = *(const float4*)(Wp2);
            w1 = *(const float4*)(Wp2 + 4);
        }

        bf16x8 af0 = *(const bf16x8*)&As[wr + l15][kof];
        bf16x8 af1 = *(const bf16x8*)&As[wr + 16 + l15][kof];
        bf16x8 bf0 = *(const bf16x8*)&Ws[wc + l15][kof];
        bf16x8 bf1 = *(const bf16x8*)&Ws[wc + 16 + l15][kof];

        acc00 = __builtin_amdgcn_mfma_f32_16x16x32_bf16(af0, bf0, acc00, 0, 0, 0);
        acc01 = __builtin_amdgcn_mfma_f32_16x16x32_bf16(af0, bf1, acc01, 0, 0, 0);
        acc10 = __builtin_amdgcn_mfma_f32_16x16x32_bf16(af1, bf0, acc10, 0, 0, 0);
        acc11 = __builtin_amdgcn_mfma_f32_16x16x32_bf16(af1, bf1, acc11, 0, 0, 0);
        __syncthreads();
    }

    // C/D layout (m89-verified): col = lane&15, row = (lane>>4)*4 + reg
    const int crow = brow + wr + ((lane >> 4) << 2);
    const int ccol = bcol + wc + l15;
    const float bias0 = bh[ccol];
    const float bias1 = bh[ccol + 16];
    #pragma unroll
    for (int r = 0; r < 4; ++r) {
        hatt[(size_t)(crow + r) * NA + ccol]           = acc00[r] + bias0;
        hatt[(size_t)(crow + r) * NA + ccol + 16]      = acc01[r] + bias1;
        hatt[(size_t)(crow + 16 + r) * NA + ccol]      = acc10[r] + bias0;
        hatt[(size_t)(crow + 16 + r) * NA + ccol + 16] = acc11[r] + bias1;
    }
}

// ---------------------------------------------------------------------------
// Kernel 2: one block per batch row b (unchanged structure; Phase B unroll 8).
// ---------------------------------------------------------------------------
__global__ __launch_bounds__(256) void attn_main_kernel(
    const float* __restrict__ features,  // [NB, NL, NA]
    const float* __restrict__ fproj,     // [NB, NL, NA]
    const float* __restrict__ wout,      // [NA]
    float* out)                          // [NB, NA]: in = h_att, out = context
{
    __shared__ float s_alpha[NL];
    __shared__ float s_red[4];

    const int t    = threadIdx.x;
    const int lane = t & 63;
    const int wid  = t >> 6;
    const int b    = blockIdx.x;

    // per-lane h_att / w_out fragments (a = lane*4 + c*256)
    const float* hrow = out + (size_t)b * NA;
    float hreg[4][4], wreg[4][4];
    #pragma unroll
    for (int c = 0; c < 4; ++c) {
        float4 h4 = *(const float4*)(hrow + c * 256 + lane * 4);
        float4 w4 = *(const float4*)(wout + c * 256 + lane * 4);
        hreg[c][0] = h4.x; hreg[c][1] = h4.y; hreg[c][2] = h4.z; hreg[c][3] = h4.w;
        wreg[c][0] = w4.x; wreg[c][1] = w4.y; wreg[c][2] = w4.z; wreg[c][3] = w4.w;
    }

    // ---- Phase A: scores ----
    const float* fpb = fproj + (size_t)b * NL * NA;
    #pragma unroll 2
    for (int l = wid; l < NL; l += 4) {
        const float* row = fpb + (size_t)l * NA + lane * 4;
        float4 f[4];
        #pragma unroll
        for (int c = 0; c < 4; ++c) f[c] = *(const float4*)(row + c * 256);
        float p = 0.f;
        #pragma unroll
        for (int c = 0; c < 4; ++c) {
            float fr[4] = {f[c].x, f[c].y, f[c].z, f[c].w};
            #pragma unroll
            for (int j = 0; j < 4; ++j)
                p = fmaf(fmaxf(hreg[c][j] + fr[j], 0.f), wreg[c][j], p);
        }
        #pragma unroll
        for (int m = 32; m; m >>= 1) p += __shfl_xor(p, m, 64);
        if (lane == 0) s_alpha[l] = p;
    }
    __syncthreads();

    // ---- softmax over NL=196 ----
    float sv = (t < NL) ? s_alpha[t] : -INFINITY;
    float mx = sv;
    #pragma unroll
    for (int m = 32; m; m >>= 1) mx = fmaxf(mx, __shfl_xor(mx, m, 64));
    if (lane == 0) s_red[wid] = mx;
    __syncthreads();
    mx = fmaxf(fmaxf(s_red[0], s_red[1]), fmaxf(s_red[2], s_red[3]));
    float e = (t < NL) ? __expf(sv - mx) : 0.f;
    float sm = e;
    #pragma unroll
    for (int m = 32; m; m >>= 1) sm += __shfl_xor(sm, m, 64);
    __syncthreads();                 // all reads of s_red done
    if (lane == 0) s_red[wid] = sm;
    __syncthreads();
    sm = s_red[0] + s_red[1] + s_red[2] + s_red[3];
    if (t < NL) s_alpha[t] = e / sm;
    __syncthreads();

    // ---- Phase B: context ----
    const float* fb = features + (size_t)b * NL * NA + t * 4;
    float4 acc = {0.f, 0.f, 0.f, 0.f};
    #pragma unroll 8
    for (int l = 0; l < NL; ++l) {
        const float al = s_alpha[l];
        float4 f = *(const float4*)(fb + (size_t)l * NA);
        acc.x = fmaf(al, f.x, acc.x);
        acc.y = fmaf(al, f.y, acc.y);
        acc.z = fmaf(al, f.z, acc.z);
        acc.w = fmaf(al, f.w, acc.w);
    }
    *(float4*)(out + (size_t)b * NA + t * 4) = acc;
}

extern "C" void kernel_launch(void* const* d_in, const int* in_sizes, int n_in,
                              void* d_out, int out_size, void* d_ws, size_t ws_size,
                              hipStream_t stream) {
    const float* features = (const float*)d_in[0];  // [1024,196,1024]
    const float* fproj    = (const float*)d_in[1];  // [1024,196,1024]
    const float* hp       = (const float*)d_in[2];  // [1024,1024]
    const float* Wh       = (const float*)d_in[3];  // [1024,1024]
    const float* bh       = (const float*)d_in[4];  // [1024]
    const float* wout     = (const float*)d_in[5];  // [1024]
    // d_in[6] = b_out: softmax(s + c) == softmax(s), provably unused.
    float* out = (float*)d_out;                     // [1024,1024]

    hatt_gemm_mfma<<<dim3(16, 16), 256, 0, stream>>>(hp, Wh, bh, out);
    attn_main_kernel<<<NB, 256, 0, stream>>>(features, fproj, wout, out);
}